// Round 11
// baseline (248.691 us; speedup 1.0000x reference)
//
#include <hip/hip_runtime.h>

#define B_ROWS 16384
#define D_IN   1024
#define NW1P   2816   // padded GEMM1 N: 10*256 expert + 3*64 gate + 64 pad
#define H2N    128

typedef unsigned short u16;
typedef __attribute__((ext_vector_type(4)))  float f32x4;
typedef __attribute__((ext_vector_type(16))) float f32x16;
typedef __attribute__((ext_vector_type(8)))  short s16x8;
typedef __attribute__((ext_vector_type(8)))  unsigned short u16x8;

__device__ __forceinline__ u16 f2bf(float f){
  unsigned int u = __float_as_uint(f);
  u += 0x7FFFu + ((u >> 16) & 1u);
  return (u16)(u >> 16);
}
__device__ __forceinline__ float bf2f(u16 h){
  return __uint_as_float(((unsigned int)h) << 16);
}

// async global->LDS, 16B per lane. LDS dest must be linear (wave base + lane*16).
__device__ __forceinline__ void gload_lds16(const void* gp, void* lp){
  typedef __attribute__((address_space(1))) unsigned int GUI;
  typedef __attribute__((address_space(3))) unsigned int LUI;
  __builtin_amdgcn_global_load_lds((GUI*)(unsigned long long)gp,
                                   (LUI*)(unsigned int)(unsigned long long)lp,
                                   16, 0, 0);
}

// ---------------- weight packing ----------------
// W1T[n][d] row-major (r2-verified)
__global__ void pack_w1_kernel(const float* __restrict__ sW1, const float* __restrict__ dW1,
                               const float* __restrict__ gW1, const float* __restrict__ sb1,
                               const float* __restrict__ db1, const float* __restrict__ gb1,
                               u16* __restrict__ W1T, float* __restrict__ b1c)
{
  __shared__ float t[64*65];
  const int tid = threadIdx.x;
  const int bid = blockIdx.x;          // 44 * 16
  const int ntile = bid >> 4, dtile = bid & 15;
  const int n0 = ntile*64, d0 = dtile*64;
  #pragma unroll
  for (int i=0;i<16;++i){
    int idx = i*256 + tid;
    int dd = idx >> 6, nn = idx & 63;
    int n = n0 + nn, d = d0 + dd;
    float v;
    if (n < 2560){
      int e = n >> 8, h = n & 255;
      v = (e < 4) ? sW1[((size_t)e*D_IN + d)*256 + h]
                  : dW1[((size_t)(e-4)*D_IN + d)*256 + h];
    } else if (n < 2752){
      int t2 = n - 2560; int gg = t2 >> 6, k = t2 & 63;
      v = gW1[((size_t)gg*D_IN + d)*64 + k];
    } else v = 0.f;
    t[nn*65 + dd] = v;
  }
  __syncthreads();
  #pragma unroll
  for (int i=0;i<16;++i){
    int idx = i*256 + tid;
    int nn = idx >> 6, dd = idx & 63;
    W1T[(size_t)(n0+nn)*D_IN + d0 + dd] = f2bf(t[nn*65 + dd]);
  }
  if (dtile == 0 && tid < 64){
    int n = n0 + tid; float v;
    if (n < 2560){ int e = n>>8, h = n&255; v = (e<4)? sb1[e*256+h] : db1[(e-4)*256+h]; }
    else if (n < 2752){ int t2 = n-2560; v = gb1[(t2>>6)*64 + (t2&63)]; }
    else v = 0.f;
    b1c[n] = v;
  }
}

// W2F: fragment-packed W2 for 32x32x16 B operand (r8-verified).
__global__ void pack_w2_kernel(const float* __restrict__ sW2, const float* __restrict__ dW2,
                               const float* __restrict__ sb2, const float* __restrict__ db2,
                               u16* __restrict__ W2F, float* __restrict__ b2c)
{
  const int tid = threadIdx.x;
  const int bid = blockIdx.x;          // 160 = 10 experts * 16
  const int e   = bid >> 4;
  const int sub = (bid & 15)*256 + tid;   // 0..4095
  const int n32 = sub >> 10, k16 = (sub >> 6) & 15, lane = sub & 63;
  const int c   = n32*32 + (lane & 31);
  const int kb  = k16*16 + (lane >> 5)*8;
  u16 out[8];
  #pragma unroll
  for (int j=0;j<8;++j){
    const int k = kb + j;
    float v = (e < 4) ? sW2[((size_t)e*256 + k)*128 + c]
                      : dW2[((size_t)(e-4)*256 + k)*128 + c];
    out[j] = f2bf(v);
  }
  *(u16x8*)&W2F[(size_t)e*32768 + (size_t)sub*8] = *(u16x8*)out;
  if ((bid & 15) == 0 && tid < 128)
    b2c[e*128 + tid] = (e < 4) ? sb2[e*128 + tid] : db2[(e-4)*128 + tid];
}

// ---------------- GEMM1: r10 core + fused f32->bf16 A-staging (cast_x eliminated) ----------------
// 8 waves (2wm x 4wn), wave 128x64, 16x16x32, 4 quadrant phases per K-tile.
// A staged from f32 x in quarter-chunks: GLAQ (2xf32x4) at ph0/ph2, WRQ (cvt_pk +
// ds_write_b128, swizzled dest) one phase later -- HBM latency hidden under MFMA,
// writes published by the per-phase lgkmcnt(0)+barrier pairs. B staged via
// global_load_lds as r10; vmcnt(0) at ph3 drains only B (2-phase slack).

#define BAR  __builtin_amdgcn_s_barrier()
#define LG0  asm volatile("s_waitcnt lgkmcnt(0)" ::: "memory")
#define LG8  asm volatile("s_waitcnt lgkmcnt(8)" ::: "memory")
#define VMW(N) asm volatile("s_waitcnt vmcnt(" #N ")" ::: "memory")

#define GLAQ(T, C) do{ \
  const float* s_ = aStgF + (T)*64 + (size_t)(C)*64*D_IN; \
  fa[C][0] = *(const f32x4*)s_; \
  fa[C][1] = *(const f32x4*)(s_ + 4); \
}while(0)

#define WRQ(C, P) do{ \
  unsigned int w0_, w1_, w2_, w3_; \
  asm("v_cvt_pk_bf16_f32 %0, %1, %2" : "=v"(w0_) : "v"(fa[C][0][0]), "v"(fa[C][0][1])); \
  asm("v_cvt_pk_bf16_f32 %0, %1, %2" : "=v"(w1_) : "v"(fa[C][0][2]), "v"(fa[C][0][3])); \
  asm("v_cvt_pk_bf16_f32 %0, %1, %2" : "=v"(w2_) : "v"(fa[C][1][0]), "v"(fa[C][1][1])); \
  asm("v_cvt_pk_bf16_f32 %0, %1, %2" : "=v"(w3_) : "v"(fa[C][1][2]), "v"(fa[C][1][3])); \
  uint4 v_; v_.x = w0_; v_.y = w1_; v_.z = w2_; v_.w = w3_; \
  *(uint4*)&L[(P)*16384 + (C)*4096 + tid*8] = v_; \
}while(0)

#define SGHB(T, P, H) do{ \
  gload_lds16(bStg + (T)*64 + (size_t)((H)*128     )*D_IN, &L[32768 + (P)*16384 + (H)*8192 + tid*8]); \
  gload_lds16(bStg + (T)*64 + (size_t)((H)*128 + 64)*D_IN, &L[32768 + (P)*16384 + (H)*8192 + 4096 + tid*8]); \
}while(0)

#define LDAQ(P, MQ) do{ \
  _Pragma("unroll") for (int mf=0;mf<4;++mf){ \
    const int rb_ = ((P)*16384) + (wm*128 + (MQ)*64 + mf*16 + fr)*64; \
    aq[mf][0] = *(const s16x8*)&L[rb_ + o0]; \
    aq[mf][1] = *(const s16x8*)&L[rb_ + o1]; } \
}while(0)
#define LDBQ(P, NQ, BQ) do{ \
  _Pragma("unroll") for (int nf=0;nf<2;++nf){ \
    const int rb_ = (32768 + (P)*16384) + (wn*64 + (NQ)*32 + nf*16 + fr)*64; \
    BQ[nf][0] = *(const s16x8*)&L[rb_ + o0]; \
    BQ[nf][1] = *(const s16x8*)&L[rb_ + o1]; } \
}while(0)

#define MFQ(MQ, NQ, BQ) do{ \
  __builtin_amdgcn_s_setprio(1); \
  _Pragma("unroll") for (int mf=0;mf<4;++mf) \
    _Pragma("unroll") for (int nf=0;nf<2;++nf){ \
      acc[(MQ)*4+mf][(NQ)*2+nf] = __builtin_amdgcn_mfma_f32_16x16x32_bf16(aq[mf][0], BQ[nf][0], acc[(MQ)*4+mf][(NQ)*2+nf],0,0,0); \
      acc[(MQ)*4+mf][(NQ)*2+nf] = __builtin_amdgcn_mfma_f32_16x16x32_bf16(aq[mf][1], BQ[nf][1], acc[(MQ)*4+mf][(NQ)*2+nf],0,0,0); } \
  __builtin_amdgcn_s_setprio(0); \
}while(0)

#define KTILE(P, Q, T1, ST) do{ \
  /* ph0: quad(m0,n0), 12 reads; issue A(t+1) f32 loads q0,q1 */ \
  LDAQ(P, 0); LDBQ(P, 0, bq0); \
  if (ST){ GLAQ(T1, 0); GLAQ(T1, 1); } \
  LG8; BAR; LG0; MFQ(0,0,bq0); BAR; \
  /* ph1: quad(m0,n1), 4 reads; cvt+write q0,q1; stage B(t+1) */ \
  LDBQ(P, 1, bq1); \
  if (ST){ WRQ(0, Q); WRQ(1, Q); SGHB(T1, Q, 0); SGHB(T1, Q, 1); } \
  BAR; LG0; MFQ(0,1,bq1); BAR; \
  /* ph2: quad(m1,n0), 8 reads; issue A(t+1) f32 loads q2,q3 */ \
  LDAQ(P, 1); \
  if (ST){ GLAQ(T1, 2); GLAQ(T1, 3); } \
  BAR; LG0; MFQ(1,0,bq0); BAR; \
  /* ph3: quad(m1,n1); cvt+write q2,q3; drain B-stage */ \
  MFQ(1,1,bq1); \
  if (ST){ WRQ(2, Q); WRQ(3, Q); } \
  LG0; VMW(0); BAR; \
}while(0)

__global__ __launch_bounds__(512, 2) void gemm1_kernel(
    const float* __restrict__ x, const u16* __restrict__ W1T,
    const float* __restrict__ b1c, u16* __restrict__ Hb)
{
  // A: buf p at p*16384; B: 32768 + p*16384 (u16 elems). 128 KiB total.
  __shared__ __attribute__((aligned(16))) u16 L[65536];
  const int tid  = threadIdx.x;
  const int lane = tid & 63;
  const int wid  = tid >> 6;
  const int wm   = wid >> 2;          // 0..1
  const int wn   = wid & 3;           // 0..3

  // 704 = 64 mt x 11 nt; per XCD mt-fast
  const int bid = blockIdx.x;
  const int xcd = bid & 7, pos = bid >> 3;
  const int mt  = xcd*8 + (pos & 7);
  const int nt  = pos >> 3;
  const int row0 = mt*256, col0 = nt*256;

  const int fr = lane & 15;           // fragment row
  const int kq = lane >> 4;           // k quarter 0..3
  const int l7 = fr & 7;
  const int o0 = ((kq     ^ l7) << 3);
  const int o1 = (((4+kq) ^ l7) << 3);

  // staging: thread -> row (tid>>3)(+64C), phys slot (tid&7); pre-swizzled source
  const int sSl = (tid & 7) ^ ((tid >> 3) & 7);
  const float* aStgF = x + (size_t)(row0 + (tid>>3))*D_IN + sSl*8;   // f32 source
  const u16*   bStg  = W1T + (size_t)(col0 + (tid>>3))*D_IN + sSl*8; // bf16 source

  f32x4 acc[8][4];
  const f32x4 fz = {0.f,0.f,0.f,0.f};
  #pragma unroll
  for (int m=0;m<8;++m)
    #pragma unroll
    for (int n=0;n<4;++n) acc[m][n] = fz;

  s16x8 aq[4][2], bq0[2][2], bq1[2][2];
  f32x4 fa[4][2];

  // prologue: stage tile 0 into buf 0 (A via reg-cvt, B via gload_lds)
  GLAQ(0, 0); GLAQ(0, 1);
  WRQ(0, 0);  WRQ(1, 0);
  GLAQ(0, 2); GLAQ(0, 3);
  WRQ(2, 0);  WRQ(3, 0);
  SGHB(0, 0, 0); SGHB(0, 0, 1);
  LG0; VMW(0); BAR;

  #pragma unroll 1
  for (int it=0; it<8; ++it){
    const int T = 2*it;
    KTILE(0, 1, T+1, 1);
    KTILE(1, 0, T+2, (it<7));
  }

  // epilogue: bias + relu + bf16 store. C/D: col=lane&15, row=(lane>>4)*4+r
  const int r4 = kq << 2;
  #pragma unroll
  for (int m=0;m<8;++m){
    const int gr = row0 + wm*128 + (m>>2)*64 + (m&3)*16 + r4;
    #pragma unroll
    for (int n=0;n<4;++n){
      const int gc = col0 + wn*64 + (n>>1)*32 + (n&1)*16 + fr;
      const float bias = b1c[gc];
      #pragma unroll
      for (int r=0;r<4;++r){
        float v = acc[m][n][r] + bias;
        v = v > 0.f ? v : 0.f;
        Hb[(size_t)(gr + r)*NW1P + gc] = f2bf(v);
      }
    }
  }
}

// ---------------- gates: softmax((relu-hidden) @ gW2 + gb2) ----------------
__global__ void gates_kernel(const u16* __restrict__ Hb, const float* __restrict__ gW2,
                             const float* __restrict__ gb2, float* __restrict__ gts)
{
  __shared__ float wsm[64*6];
  __shared__ float bsm[6];
  const int tid = threadIdx.x;
  const int bid = blockIdx.x;                 // 3 * 64 blocks
  const int g = bid >> 6;
  const int b = ((bid & 63) << 8) + tid;
  if (tid < 6) bsm[tid] = gb2[g*6 + tid];
  for (int i = tid; i < 384; i += 256) wsm[i] = gW2[g*384 + i];
  __syncthreads();
  const u16* gh = Hb + (size_t)b*NW1P + 2560 + g*64;
  float lg[6];
  #pragma unroll
  for (int e=0;e<6;++e) lg[e] = bsm[e];
  #pragma unroll
  for (int k8=0;k8<8;++k8){
    u16x8 hv = *(const u16x8*)&gh[k8*8];
    #pragma unroll
    for (int j=0;j<8;++j){
      const float h = bf2f(hv[j]);
      const int k = k8*8 + j;
      #pragma unroll
      for (int e=0;e<6;++e) lg[e] += h * wsm[k*6 + e];
    }
  }
  float mx = lg[0];
  #pragma unroll
  for (int e=1;e<6;++e) mx = fmaxf(mx, lg[e]);
  float s = 0.f; float p[6];
  #pragma unroll
  for (int e=0;e<6;++e){ p[e] = expf(lg[e]-mx); s += p[e]; }
  const float inv = 1.f / s;
  float* dst = gts + ((size_t)g*B_ROWS + b)*6;
  #pragma unroll
  for (int e=0;e<6;++e) dst[e] = p[e]*inv;
}

// ------- GEMM2 deduped: block = 64 rows x 128 cols, ALL 3 domains, 10 physical experts -------
// Shared experts (0..3) computed ONCE and fanned into all 3 domain outputs (reference
// semantics; r1-r10 recomputed them 3x). FLOPs 19.3->10.7 GF, Hb reads 151->84 MB.
// 4 waves (col strips of 32); A=Hb LDS dbuf; B=W2F frags in regs; counted vmcnt(4).
// Expert loop FULLY UNROLLED so oacc[g] indexing is compile-time (rule #20).

#define SGA2(S, BUF) do{ \
  const u16* ga_ = Hb + (size_t)(row0 + (tid>>3))*NW1P + ((S)>>2)*256 + ((S)&3)*64 + sSl2*8; \
  gload_lds16(ga_,                   &LA[BUF][tid*8]); \
  gload_lds16(ga_ + (size_t)32*NW1P, &LA[BUF][2048 + tid*8]); \
}while(0)

#define LOADB2(S, BV) do{ \
  const size_t base_ = ((size_t)(((S)>>2)*4 + wn)*16 + ((S)&3)*4)*512; \
  _Pragma("unroll") for (int kk=0;kk<4;++kk) \
    BV[kk] = *(const s16x8*)(pB2 + base_ + kk*512); \
}while(0)

#define COMPUTE2(BUF, BV) do{ \
  _Pragma("unroll") for (int kk=0;kk<4;++kk){ \
    s16x8 av[2]; \
    _Pragma("unroll") for (int mf=0;mf<2;++mf){ \
      const int row_ = mf*32 + l31; \
      av[mf] = *(const s16x8*)&LA[BUF][(row_<<6) + (((((kk<<1)|l5)) ^ (row_&7))<<3)]; \
    } \
    __builtin_amdgcn_s_setprio(1); \
    eacc[0] = __builtin_amdgcn_mfma_f32_32x32x16_bf16(av[0], BV[kk], eacc[0], 0, 0, 0); \
    eacc[1] = __builtin_amdgcn_mfma_f32_32x32x16_bf16(av[1], BV[kk], eacc[1], 0, 0, 0); \
    __builtin_amdgcn_s_setprio(0); \
  } \
}while(0)

#define EPI2(PE) do{ \
  const float bias_ = bsm[(PE)*128 + wn*32 + l31]; \
  _Pragma("unroll") for (int mf=0;mf<2;++mf){ \
    _Pragma("unroll") for (int r=0;r<16;++r){ \
      const int rl_ = mf*32 + 4*l5 + (r&3) + 8*(r>>2); \
      float v = eacc[mf][r] + bias_; \
      v = v > 0.f ? v : 0.f; \
      if ((PE) < 4){ \
        oacc[0][mf][r] += gsm[0*384 + rl_*6 + (PE)] * v; \
        oacc[1][mf][r] += gsm[1*384 + rl_*6 + (PE)] * v; \
        oacc[2][mf][r] += gsm[2*384 + rl_*6 + (PE)] * v; \
      } else { \
        oacc[((PE)-4)>>1][mf][r] += gsm[((((PE)-4)>>1))*384 + rl_*6 + 4 + (((PE)-4)&1)] * v; \
      } \
      eacc[mf][r] = 0.f; \
    } \
  } \
}while(0)

__global__ __launch_bounds__(256, 1) void gemm2_kernel(
    const u16* __restrict__ Hb, const u16* __restrict__ W2F,
    const float* __restrict__ b2c, const float* __restrict__ gts,
    float* __restrict__ outp)
{
  __shared__ __attribute__((aligned(16))) u16 LA[2][4096];  // 2 x 8 KB (64 rows x 64 k)
  __shared__ float gsm[3*384];     // gates: [g][64 rows][6]
  __shared__ float bsm[10*128];    // biases for all 10 physical experts
  const int tid  = threadIdx.x;
  const int lane = tid & 63;
  const int wn   = tid >> 6;          // 0..3 (col strip of 32)
  const int l31  = lane & 31, l5 = lane >> 5;

  const int bid  = blockIdx.x;        // 256 blocks = 1 per CU exactly
  const int row0 = bid*64;

  const int sSl2 = (tid & 7) ^ ((tid >> 3) & 7);
  const u16* pB2 = W2F + lane*8;

  #pragma unroll
  for (int g=0; g<3; ++g)
    for (int i = tid; i < 384; i += 256)
      gsm[g*384 + i] = gts[((size_t)g*B_ROWS + row0)*6 + i];
  for (int i = tid; i < 1280; i += 256) bsm[i] = b2c[i];

  f32x16 eacc[2], oacc[3][2];
  #pragma unroll
  for (int mf=0;mf<2;++mf)
    #pragma unroll
    for (int r=0;r<16;++r){
      eacc[mf][r] = 0.f;
      oacc[0][mf][r] = 0.f; oacc[1][mf][r] = 0.f; oacc[2][mf][r] = 0.f;
    }

  s16x8 bvA[4], bvB[4];

  SGA2(0, 0);
  LOADB2(0, bvA);
  VMW(0); BAR;

  #pragma unroll
  for (int i=0; i<20; ++i){           // fully unrolled: PE compile-time in EPI2
    const int s = 2*i;
    SGA2(s+1, 1);
    LOADB2(s+1, bvB);
    COMPUTE2(0, bvA);
    VMW(4); BAR;
    if (i < 19){ SGA2(s+2, 0); LOADB2(s+2, bvA); }
    COMPUTE2(1, bvB);
    if (((s+1) & 3) == 3) EPI2((s+1) >> 2);
    VMW(4); BAR;
  }

  // store all 3 domain outputs
  #pragma unroll
  for (int g=0; g<3; ++g){
    #pragma unroll
    for (int mf=0;mf<2;++mf){
      #pragma unroll
      for (int r=0;r<16;++r){
        const int rl = mf*32 + 4*l5 + (r&3) + 8*(r>>2);
        outp[((size_t)g*B_ROWS + row0 + rl)*H2N + wn*32 + l31] = oacc[g][mf][r];
      }
    }
  }
}

extern "C" void kernel_launch(void* const* d_in, const int* in_sizes, int n_in,
                              void* d_out, int out_size, void* d_ws, size_t ws_size,
                              hipStream_t stream)
{
  (void)in_sizes; (void)n_in; (void)out_size; (void)ws_size;
  const float* x   = (const float*)d_in[0];
  const float* sW1 = (const float*)d_in[2];
  const float* sb1 = (const float*)d_in[3];
  const float* sW2 = (const float*)d_in[4];
  const float* sb2 = (const float*)d_in[5];
  const float* dW1 = (const float*)d_in[6];
  const float* db1 = (const float*)d_in[7];
  const float* dW2 = (const float*)d_in[8];
  const float* db2 = (const float*)d_in[9];
  const float* gW1 = (const float*)d_in[10];
  const float* gb1 = (const float*)d_in[11];
  const float* gW2 = (const float*)d_in[12];
  const float* gb2 = (const float*)d_in[13];
  float* outp = (float*)d_out;

  char* ws = (char*)d_ws;
  u16*   W1T = (u16*  )(ws + 0);         // 2816*1024*2 = 5767168
  float* b1c = (float*)(ws + 5767168);   // 2816*4      =   11264
  u16*   W2F = (u16*  )(ws + 5778432);   // 10*4096*8*2 =  655360
  float* b2c = (float*)(ws + 6433792);   // 10*128*4    =    5120
  float* gts = (float*)(ws + 6438912);   // 3*16384*6*4 = 1179648
  u16*   Hb  = (u16*  )(ws + 7618560);   // 16384*2816*2 = 92274688 (end ~99.9 MB)

  pack_w1_kernel<<<dim3(704), dim3(256), 0, stream>>>(sW1,dW1,gW1,sb1,db1,gb1,W1T,b1c);
  pack_w2_kernel<<<dim3(160), dim3(256), 0, stream>>>(sW2,dW2,sb2,db2,W2F,b2c);
  gemm1_kernel  <<<dim3(704), dim3(512), 0, stream>>>(x, W1T, b1c, Hb);
  gates_kernel  <<<dim3(192), dim3(256), 0, stream>>>(Hb, gW2, gb2, gts);
  gemm2_kernel  <<<dim3(256), dim3(256), 0, stream>>>(Hb, W2F, b2c, gts, outp);
}

// Round 12
// 159.018 us; speedup vs baseline: 1.5639x; 1.5639x over previous
//
#include <hip/hip_runtime.h>

#define B_ROWS 16384
#define D_IN   1024
#define NW1P   2816   // padded GEMM1 N: 10*256 expert + 3*64 gate + 64 pad
#define H2N    128

typedef unsigned short u16;
typedef __attribute__((ext_vector_type(4)))  float f32x4;
typedef __attribute__((ext_vector_type(16))) float f32x16;
typedef __attribute__((ext_vector_type(8)))  short s16x8;
typedef __attribute__((ext_vector_type(8)))  unsigned short u16x8;

__device__ __forceinline__ u16 f2bf(float f){
  unsigned int u = __float_as_uint(f);
  u += 0x7FFFu + ((u >> 16) & 1u);
  return (u16)(u >> 16);
}
__device__ __forceinline__ float bf2f(u16 h){
  return __uint_as_float(((unsigned int)h) << 16);
}

// async global->LDS, 16B per lane. LDS dest must be linear (wave base + lane*16).
__device__ __forceinline__ void gload_lds16(const void* gp, void* lp){
  typedef __attribute__((address_space(1))) unsigned int GUI;
  typedef __attribute__((address_space(3))) unsigned int LUI;
  __builtin_amdgcn_global_load_lds((GUI*)(unsigned long long)gp,
                                   (LUI*)(unsigned int)(unsigned long long)lp,
                                   16, 0, 0);
}

// ---------------- weight packing ----------------
// W1T[n][d] row-major (r2-verified)
__global__ void pack_w1_kernel(const float* __restrict__ sW1, const float* __restrict__ dW1,
                               const float* __restrict__ gW1, const float* __restrict__ sb1,
                               const float* __restrict__ db1, const float* __restrict__ gb1,
                               u16* __restrict__ W1T, float* __restrict__ b1c)
{
  __shared__ float t[64*65];
  const int tid = threadIdx.x;
  const int bid = blockIdx.x;          // 44 * 16
  const int ntile = bid >> 4, dtile = bid & 15;
  const int n0 = ntile*64, d0 = dtile*64;
  #pragma unroll
  for (int i=0;i<16;++i){
    int idx = i*256 + tid;
    int dd = idx >> 6, nn = idx & 63;
    int n = n0 + nn, d = d0 + dd;
    float v;
    if (n < 2560){
      int e = n >> 8, h = n & 255;
      v = (e < 4) ? sW1[((size_t)e*D_IN + d)*256 + h]
                  : dW1[((size_t)(e-4)*D_IN + d)*256 + h];
    } else if (n < 2752){
      int t2 = n - 2560; int gg = t2 >> 6, k = t2 & 63;
      v = gW1[((size_t)gg*D_IN + d)*64 + k];
    } else v = 0.f;
    t[nn*65 + dd] = v;
  }
  __syncthreads();
  #pragma unroll
  for (int i=0;i<16;++i){
    int idx = i*256 + tid;
    int nn = idx >> 6, dd = idx & 63;
    W1T[(size_t)(n0+nn)*D_IN + d0 + dd] = f2bf(t[nn*65 + dd]);
  }
  if (dtile == 0 && tid < 64){
    int n = n0 + tid; float v;
    if (n < 2560){ int e = n>>8, h = n&255; v = (e<4)? sb1[e*256+h] : db1[(e-4)*256+h]; }
    else if (n < 2752){ int t2 = n-2560; v = gb1[(t2>>6)*64 + (t2&63)]; }
    else v = 0.f;
    b1c[n] = v;
  }
}

// W2F: fragment-packed W2 for 32x32x16 B operand (r8-verified).
__global__ void pack_w2_kernel(const float* __restrict__ sW2, const float* __restrict__ dW2,
                               const float* __restrict__ sb2, const float* __restrict__ db2,
                               u16* __restrict__ W2F, float* __restrict__ b2c)
{
  const int tid = threadIdx.x;
  const int bid = blockIdx.x;          // 160 = 10 experts * 16
  const int e   = bid >> 4;
  const int sub = (bid & 15)*256 + tid;   // 0..4095
  const int n32 = sub >> 10, k16 = (sub >> 6) & 15, lane = sub & 63;
  const int c   = n32*32 + (lane & 31);
  const int kb  = k16*16 + (lane >> 5)*8;
  u16 out[8];
  #pragma unroll
  for (int j=0;j<8;++j){
    const int k = kb + j;
    float v = (e < 4) ? sW2[((size_t)e*256 + k)*128 + c]
                      : dW2[((size_t)(e-4)*256 + k)*128 + c];
    out[j] = f2bf(v);
  }
  *(u16x8*)&W2F[(size_t)e*32768 + (size_t)sub*8] = *(u16x8*)out;
  if ((bid & 15) == 0 && tid < 128)
    b2c[e*128 + tid] = (e < 4) ? sb2[e*128 + tid] : db2[(e-4)*128 + tid];
}

__global__ void cast_x_kernel(const float* __restrict__ x, u16* __restrict__ xb)
{
  const size_t i = ((size_t)blockIdx.x*256 + threadIdx.x)*8;
  f32x4 a = *(const f32x4*)(x + i);
  f32x4 b = *(const f32x4*)(x + i + 4);
  u16x8 r;
  r[0]=f2bf(a[0]); r[1]=f2bf(a[1]); r[2]=f2bf(a[2]); r[3]=f2bf(a[3]);
  r[4]=f2bf(b[0]); r[5]=f2bf(b[1]); r[6]=f2bf(b[2]); r[7]=f2bf(b[3]);
  *(u16x8*)(xb + i) = r;
}

// ---------------- GEMM1: r10 core (best measured: ~115 us, MfmaUtil 33) ----------------
#define BAR  __builtin_amdgcn_s_barrier()
#define LG0  asm volatile("s_waitcnt lgkmcnt(0)" ::: "memory")
#define LG8  asm volatile("s_waitcnt lgkmcnt(8)" ::: "memory")
#define VMW(N) asm volatile("s_waitcnt vmcnt(" #N ")" ::: "memory")

#define SGHA(T, P, H) do{ \
  gload_lds16(aStg + (T)*64 + (size_t)((H)*128     )*D_IN, &L[(P)*16384 + (H)*8192 + tid*8]); \
  gload_lds16(aStg + (T)*64 + (size_t)((H)*128 + 64)*D_IN, &L[(P)*16384 + (H)*8192 + 4096 + tid*8]); \
}while(0)
#define SGHB(T, P, H) do{ \
  gload_lds16(bStg + (T)*64 + (size_t)((H)*128     )*D_IN, &L[32768 + (P)*16384 + (H)*8192 + tid*8]); \
  gload_lds16(bStg + (T)*64 + (size_t)((H)*128 + 64)*D_IN, &L[32768 + (P)*16384 + (H)*8192 + 4096 + tid*8]); \
}while(0)

#define LDAQ(P, MQ) do{ \
  _Pragma("unroll") for (int mf=0;mf<4;++mf){ \
    const int rb_ = ((P)*16384) + (wm*128 + (MQ)*64 + mf*16 + fr)*64; \
    aq[mf][0] = *(const s16x8*)&L[rb_ + o0]; \
    aq[mf][1] = *(const s16x8*)&L[rb_ + o1]; } \
}while(0)
#define LDBQ(P, NQ, BQ) do{ \
  _Pragma("unroll") for (int nf=0;nf<2;++nf){ \
    const int rb_ = (32768 + (P)*16384) + (wn*64 + (NQ)*32 + nf*16 + fr)*64; \
    BQ[nf][0] = *(const s16x8*)&L[rb_ + o0]; \
    BQ[nf][1] = *(const s16x8*)&L[rb_ + o1]; } \
}while(0)

#define MFQ(MQ, NQ, BQ) do{ \
  __builtin_amdgcn_s_setprio(1); \
  _Pragma("unroll") for (int mf=0;mf<4;++mf) \
    _Pragma("unroll") for (int nf=0;nf<2;++nf){ \
      acc[(MQ)*4+mf][(NQ)*2+nf] = __builtin_amdgcn_mfma_f32_16x16x32_bf16(aq[mf][0], BQ[nf][0], acc[(MQ)*4+mf][(NQ)*2+nf],0,0,0); \
      acc[(MQ)*4+mf][(NQ)*2+nf] = __builtin_amdgcn_mfma_f32_16x16x32_bf16(aq[mf][1], BQ[nf][1], acc[(MQ)*4+mf][(NQ)*2+nf],0,0,0); } \
  __builtin_amdgcn_s_setprio(0); \
}while(0)

#define KTILE(P, Q, T1, ST) do{ \
  LDAQ(P, 0); LDBQ(P, 0, bq0); \
  if (ST){ SGHA(T1, Q, 0); SGHA(T1, Q, 1); } \
  LG8; BAR; LG0; MFQ(0,0,bq0); BAR; \
  LDBQ(P, 1, bq1); \
  if (ST){ SGHB(T1, Q, 0); SGHB(T1, Q, 1); } \
  BAR; LG0; MFQ(0,1,bq1); BAR; \
  LDAQ(P, 1); \
  BAR; LG0; MFQ(1,0,bq0); VMW(4); BAR; \
  MFQ(1,1,bq1); VMW(0); BAR; \
}while(0)

__global__ __launch_bounds__(512, 2) void gemm1_kernel(
    const u16* __restrict__ Xb, const u16* __restrict__ W1T,
    const float* __restrict__ b1c, u16* __restrict__ Hb)
{
  __shared__ __attribute__((aligned(16))) u16 L[65536];
  const int tid  = threadIdx.x;
  const int lane = tid & 63;
  const int wid  = tid >> 6;
  const int wm   = wid >> 2;          // 0..1
  const int wn   = wid & 3;           // 0..3

  const int bid = blockIdx.x;
  const int xcd = bid & 7, pos = bid >> 3;
  const int mt  = xcd*8 + (pos & 7);
  const int nt  = pos >> 3;
  const int row0 = mt*256, col0 = nt*256;

  const int fr = lane & 15;
  const int kq = lane >> 4;
  const int l7 = fr & 7;
  const int o0 = ((kq     ^ l7) << 3);
  const int o1 = (((4+kq) ^ l7) << 3);

  const int sSl = (tid & 7) ^ ((tid >> 3) & 7);
  const u16* aStg = Xb  + (size_t)(row0 + (tid>>3))*D_IN + sSl*8;
  const u16* bStg = W1T + (size_t)(col0 + (tid>>3))*D_IN + sSl*8;

  f32x4 acc[8][4];
  const f32x4 fz = {0.f,0.f,0.f,0.f};
  #pragma unroll
  for (int m=0;m<8;++m)
    #pragma unroll
    for (int n=0;n<4;++n) acc[m][n] = fz;

  s16x8 aq[4][2], bq0[2][2], bq1[2][2];

  SGHA(0, 0, 0); SGHA(0, 0, 1);
  SGHB(0, 0, 0); SGHB(0, 0, 1);
  VMW(0); BAR;

  #pragma unroll 1
  for (int it=0; it<8; ++it){
    const int T = 2*it;
    KTILE(0, 1, T+1, 1);
    KTILE(1, 0, T+2, (it<7));
  }

  const int r4 = kq << 2;
  #pragma unroll
  for (int m=0;m<8;++m){
    const int gr = row0 + wm*128 + (m>>2)*64 + (m&3)*16 + r4;
    #pragma unroll
    for (int n=0;n<4;++n){
      const int gc = col0 + wn*64 + (n>>1)*32 + (n&1)*16 + fr;
      const float bias = b1c[gc];
      #pragma unroll
      for (int r=0;r<4;++r){
        float v = acc[m][n][r] + bias;
        v = v > 0.f ? v : 0.f;
        Hb[(size_t)(gr + r)*NW1P + gc] = f2bf(v);
      }
    }
  }
}

// ---------------- gates: softmax((relu-hidden) @ gW2 + gb2) ----------------
__global__ void gates_kernel(const u16* __restrict__ Hb, const float* __restrict__ gW2,
                             const float* __restrict__ gb2, float* __restrict__ gts)
{
  __shared__ float wsm[64*6];
  __shared__ float bsm[6];
  const int tid = threadIdx.x;
  const int bid = blockIdx.x;                 // 3 * 64 blocks
  const int g = bid >> 6;
  const int b = ((bid & 63) << 8) + tid;
  if (tid < 6) bsm[tid] = gb2[g*6 + tid];
  for (int i = tid; i < 384; i += 256) wsm[i] = gW2[g*384 + i];
  __syncthreads();
  const u16* gh = Hb + (size_t)b*NW1P + 2560 + g*64;
  float lg[6];
  #pragma unroll
  for (int e=0;e<6;++e) lg[e] = bsm[e];
  #pragma unroll
  for (int k8=0;k8<8;++k8){
    u16x8 hv = *(const u16x8*)&gh[k8*8];
    #pragma unroll
    for (int j=0;j<8;++j){
      const float h = bf2f(hv[j]);
      const int k = k8*8 + j;
      #pragma unroll
      for (int e=0;e<6;++e) lg[e] += h * wsm[k*6 + e];
    }
  }
  float mx = lg[0];
  #pragma unroll
  for (int e=1;e<6;++e) mx = fmaxf(mx, lg[e]);
  float s = 0.f; float p[6];
  #pragma unroll
  for (int e=0;e<6;++e){ p[e] = expf(lg[e]-mx); s += p[e]; }
  const float inv = 1.f / s;
  float* dst = gts + ((size_t)g*B_ROWS + b)*6;
  #pragma unroll
  for (int e=0;e<6;++e) dst[e] = p[e]*inv;
}

// ------- GEMM2 deduped v3: 256 blocks x 512 threads; shared experts computed ONCE -------
// 8 waves = 2 row-halves (wh) x 4 col strips (wn); wave tile 32x32.
// eacc(16) + oacc[3](48) = 64 acc VGPRs -> no spill (r11 lesson: 128 acc at 256thr spilled).
// 40 K-subtiles = 10 physical experts x 4; fully unrolled (compile-time expert in EPI).
// A = Hb via LDS dbuf (1 gld_lds/thread/subtile); B = W2F frags in regs; counted vmcnt(4).

#define SGA2(S, BUF) do{ \
  const u16* ga_ = Hb + (size_t)(row0 + (tid>>3))*NW1P + ((S)>>2)*256 + ((S)&3)*64 + sSl2*8; \
  gload_lds16(ga_, &LA[BUF][tid*8]); \
}while(0)

#define LOADB2(S, BV) do{ \
  const size_t base_ = ((size_t)(((S)>>2)*4 + wn)*16 + ((S)&3)*4)*512; \
  _Pragma("unroll") for (int kk=0;kk<4;++kk) \
    BV[kk] = *(const s16x8*)(pB2 + base_ + kk*512); \
}while(0)

#define COMPUTE2(BUF, BV) do{ \
  _Pragma("unroll") for (int kk=0;kk<4;++kk){ \
    const int row_ = wh*32 + l31; \
    s16x8 av = *(const s16x8*)&LA[BUF][(row_<<6) + (((((kk<<1)|l5)) ^ (row_&7))<<3)]; \
    __builtin_amdgcn_s_setprio(1); \
    eacc = __builtin_amdgcn_mfma_f32_32x32x16_bf16(av, BV[kk], eacc, 0, 0, 0); \
    __builtin_amdgcn_s_setprio(0); \
  } \
}while(0)

#define EPI2(PE) do{ \
  const float bias_ = bsm[(PE)*128 + wn*32 + l31]; \
  _Pragma("unroll") for (int r=0;r<16;++r){ \
    const int rl_ = wh*32 + 4*l5 + (r&3) + 8*(r>>2); \
    float v = eacc[r] + bias_; \
    v = v > 0.f ? v : 0.f; \
    if ((PE) < 4){ \
      oacc[0][r] += gsm[0*384 + rl_*6 + (PE)] * v; \
      oacc[1][r] += gsm[1*384 + rl_*6 + (PE)] * v; \
      oacc[2][r] += gsm[2*384 + rl_*6 + (PE)] * v; \
    } else { \
      oacc[((PE)-4)>>1][r] += gsm[(((PE)-4)>>1)*384 + rl_*6 + 4 + (((PE)-4)&1)] * v; \
    } \
    eacc[r] = 0.f; \
  } \
}while(0)

__global__ __launch_bounds__(512, 2) void gemm2_kernel(
    const u16* __restrict__ Hb, const u16* __restrict__ W2F,
    const float* __restrict__ b2c, const float* __restrict__ gts,
    float* __restrict__ outp)
{
  __shared__ __attribute__((aligned(16))) u16 LA[2][4096];  // 2 x 8 KB (64 rows x 64 k)
  __shared__ float gsm[1152];      // gates: [g][64 rows][6]
  __shared__ float bsm[1280];      // biases for 10 physical experts
  const int tid  = threadIdx.x;
  const int lane = tid & 63;
  const int wid  = tid >> 6;
  const int wh   = wid >> 2;          // 0..1 row half
  const int wn   = wid & 3;           // 0..3 col strip
  const int l31  = lane & 31, l5 = lane >> 5;

  const int bid  = blockIdx.x;        // 256 blocks: one 64-row band each
  const int row0 = bid*64;

  const int sSl2 = (tid & 7) ^ ((tid >> 3) & 7);
  const u16* pB2 = W2F + lane*8;

  for (int i = tid; i < 1152; i += 512){
    const int g = i/384, rem = i - g*384;
    gsm[i] = gts[((size_t)g*B_ROWS + row0)*6 + rem];
  }
  for (int i = tid; i < 1280; i += 512) bsm[i] = b2c[i];

  f32x16 eacc, oacc[3];
  #pragma unroll
  for (int r=0;r<16;++r){
    eacc[r] = 0.f; oacc[0][r] = 0.f; oacc[1][r] = 0.f; oacc[2][r] = 0.f;
  }

  s16x8 bvA[4], bvB[4];

  SGA2(0, 0);
  LOADB2(0, bvA);
  __syncthreads();            // drains vmcnt+lgkmcnt (stage 0 + gsm/bsm visible)

  #pragma unroll
  for (int i=0; i<20; ++i){   // fully unrolled: S and PE compile-time
    const int s = 2*i;
    SGA2(s+1, 1);
    LOADB2(s+1, bvB);
    COMPUTE2(0, bvA);
    VMW(4); BAR;
    if (i < 19){ SGA2(s+2, 0); LOADB2(s+2, bvA); }
    COMPUTE2(1, bvB);
    if (((s+1) & 3) == 3) EPI2((s+1) >> 2);
    VMW(4); BAR;
  }

  #pragma unroll
  for (int g=0; g<3; ++g){
    #pragma unroll
    for (int r=0;r<16;++r){
      const int rl = wh*32 + 4*l5 + (r&3) + 8*(r>>2);
      outp[((size_t)g*B_ROWS + row0 + rl)*H2N + wn*32 + l31] = oacc[g][r];
    }
  }
}

extern "C" void kernel_launch(void* const* d_in, const int* in_sizes, int n_in,
                              void* d_out, int out_size, void* d_ws, size_t ws_size,
                              hipStream_t stream)
{
  (void)in_sizes; (void)n_in; (void)out_size; (void)ws_size;
  const float* x   = (const float*)d_in[0];
  const float* sW1 = (const float*)d_in[2];
  const float* sb1 = (const float*)d_in[3];
  const float* sW2 = (const float*)d_in[4];
  const float* sb2 = (const float*)d_in[5];
  const float* dW1 = (const float*)d_in[6];
  const float* db1 = (const float*)d_in[7];
  const float* dW2 = (const float*)d_in[8];
  const float* db2 = (const float*)d_in[9];
  const float* gW1 = (const float*)d_in[10];
  const float* gb1 = (const float*)d_in[11];
  const float* gW2 = (const float*)d_in[12];
  const float* gb2 = (const float*)d_in[13];
  float* outp = (float*)d_out;

  char* ws = (char*)d_ws;
  u16*   Xb  = (u16*  )(ws + 0);          // 16384*1024*2 = 33554432
  u16*   W1T = (u16*  )(ws + 33554432);   // 2816*1024*2  =  5767168
  float* b1c = (float*)(ws + 39321600);   // 2816*4       =    11264
  u16*   W2F = (u16*  )(ws + 39332864);   // 10*4096*8*2  =   655360
  float* b2c = (float*)(ws + 39988224);   // 10*128*4     =     5120
  float* gts = (float*)(ws + 39993344);   // 3*16384*6*4  =  1179648
  u16*   Hb  = (u16*  )(ws + 41172992);   // 16384*2816*2 = 92274688

  pack_w1_kernel<<<dim3(704),  dim3(256), 0, stream>>>(sW1,dW1,gW1,sb1,db1,gb1,W1T,b1c);
  pack_w2_kernel<<<dim3(160),  dim3(256), 0, stream>>>(sW2,dW2,sb2,db2,W2F,b2c);
  cast_x_kernel <<<dim3(8192), dim3(256), 0, stream>>>(x, Xb);
  gemm1_kernel  <<<dim3(704),  dim3(512), 0, stream>>>(Xb, W1T, b1c, Hb);
  gates_kernel  <<<dim3(192),  dim3(256), 0, stream>>>(Hb, gW2, gb2, gts);
  gemm2_kernel  <<<dim3(256),  dim3(512), 0, stream>>>(Hb, W2F, b2c, gts, outp);
}

// Round 13
// 148.279 us; speedup vs baseline: 1.6772x; 1.0724x over previous
//
#include <hip/hip_runtime.h>

#define B_ROWS 16384
#define D_IN   1024
#define NW1P   2816   // padded GEMM1 N: 10*256 expert + 3*64 gate + 64 pad
#define H2N    128

typedef unsigned short u16;
typedef __attribute__((ext_vector_type(4)))  float f32x4;
typedef __attribute__((ext_vector_type(16))) float f32x16;
typedef __attribute__((ext_vector_type(8)))  short s16x8;
typedef __attribute__((ext_vector_type(8)))  unsigned short u16x8;

__device__ __forceinline__ u16 f2bf(float f){
  unsigned int u = __float_as_uint(f);
  u += 0x7FFFu + ((u >> 16) & 1u);
  return (u16)(u >> 16);
}
__device__ __forceinline__ float bf2f(u16 h){
  return __uint_as_float(((unsigned int)h) << 16);
}

// async global->LDS, 16B per lane. LDS dest must be linear (wave base + lane*16).
__device__ __forceinline__ void gload_lds16(const void* gp, void* lp){
  typedef __attribute__((address_space(1))) unsigned int GUI;
  typedef __attribute__((address_space(3))) unsigned int LUI;
  __builtin_amdgcn_global_load_lds((GUI*)(unsigned long long)gp,
                                   (LUI*)(unsigned int)(unsigned long long)lp,
                                   16, 0, 0);
}

// ---------------- merged prep: pack_w1 | pack_w2 | cast_x in one dispatch ----------------
__global__ void prep_kernel(const float* __restrict__ sW1, const float* __restrict__ dW1,
                            const float* __restrict__ gW1, const float* __restrict__ sb1,
                            const float* __restrict__ db1, const float* __restrict__ gb1,
                            u16* __restrict__ W1T, float* __restrict__ b1c,
                            const float* __restrict__ sW2, const float* __restrict__ dW2,
                            const float* __restrict__ sb2, const float* __restrict__ db2,
                            u16* __restrict__ W2F, float* __restrict__ b2c,
                            const float* __restrict__ x, u16* __restrict__ Xb)
{
  __shared__ float t[64*65];
  const int tid = threadIdx.x;
  const int bidg = blockIdx.x;

  if (bidg < 704){
    // ---- pack_w1: W1T[n][d] row-major bf16 (r2-verified) ----
    const int bid = bidg;
    const int ntile = bid >> 4, dtile = bid & 15;
    const int n0 = ntile*64, d0 = dtile*64;
    #pragma unroll
    for (int i=0;i<16;++i){
      int idx = i*256 + tid;
      int dd = idx >> 6, nn = idx & 63;
      int n = n0 + nn, d = d0 + dd;
      float v;
      if (n < 2560){
        int e = n >> 8, h = n & 255;
        v = (e < 4) ? sW1[((size_t)e*D_IN + d)*256 + h]
                    : dW1[((size_t)(e-4)*D_IN + d)*256 + h];
      } else if (n < 2752){
        int t2 = n - 2560; int gg = t2 >> 6, k = t2 & 63;
        v = gW1[((size_t)gg*D_IN + d)*64 + k];
      } else v = 0.f;
      t[nn*65 + dd] = v;
    }
    __syncthreads();
    #pragma unroll
    for (int i=0;i<16;++i){
      int idx = i*256 + tid;
      int nn = idx >> 6, dd = idx & 63;
      W1T[(size_t)(n0+nn)*D_IN + d0 + dd] = f2bf(t[nn*65 + dd]);
    }
    if (dtile == 0 && tid < 64){
      int n = n0 + tid; float v;
      if (n < 2560){ int e = n>>8, h = n&255; v = (e<4)? sb1[e*256+h] : db1[(e-4)*256+h]; }
      else if (n < 2752){ int t2 = n-2560; v = gb1[(t2>>6)*64 + (t2&63)]; }
      else v = 0.f;
      b1c[n] = v;
    }
  } else if (bidg < 864){
    // ---- pack_w2: W2F fragment-packed (r8-verified) ----
    const int bid = bidg - 704;          // 0..159
    const int e   = bid >> 4;
    const int sub = (bid & 15)*256 + tid;
    const int n32 = sub >> 10, k16 = (sub >> 6) & 15, lane = sub & 63;
    const int c   = n32*32 + (lane & 31);
    const int kb  = k16*16 + (lane >> 5)*8;
    u16 out[8];
    #pragma unroll
    for (int j=0;j<8;++j){
      const int k = kb + j;
      float v = (e < 4) ? sW2[((size_t)e*256 + k)*128 + c]
                        : dW2[((size_t)(e-4)*256 + k)*128 + c];
      out[j] = f2bf(v);
    }
    *(u16x8*)&W2F[(size_t)e*32768 + (size_t)sub*8] = *(u16x8*)out;
    if ((bid & 15) == 0 && tid < 128)
      b2c[e*128 + tid] = (e < 4) ? sb2[e*128 + tid] : db2[(e-4)*128 + tid];
  } else {
    // ---- cast_x ----
    const size_t i = ((size_t)(bidg - 864)*256 + tid)*8;
    f32x4 a = *(const f32x4*)(x + i);
    f32x4 b = *(const f32x4*)(x + i + 4);
    u16x8 r;
    r[0]=f2bf(a[0]); r[1]=f2bf(a[1]); r[2]=f2bf(a[2]); r[3]=f2bf(a[3]);
    r[4]=f2bf(b[0]); r[5]=f2bf(b[1]); r[6]=f2bf(b[2]); r[7]=f2bf(b[3]);
    *(u16x8*)(Xb + i) = r;
  }
}

// ---------------- GEMM1: 256x256, BK=64, 16x16x32, ONE barrier + ONE vmcnt per K-tile ----
// r10 addressing (0-conflict swizzle, mt-major 71MB mapping) but NO intra-tile barriers:
// 24 ds_read_b128 + 32 MFMA per wave per tile are compiler-scheduled via counted lgkmcnt,
// so waves on a SIMD drift within the tile and LDS/matrix pipes overlap cross-wave
// (removes the lockstep {LDS-burst | MFMA-burst} alternation = 5 schedules' shared 33% cap).

#define BAR  __builtin_amdgcn_s_barrier()
#define VMW(N) asm volatile("s_waitcnt vmcnt(" #N ")" ::: "memory")

#define SGHA(T, P, H) do{ \
  gload_lds16(aStg + (T)*64 + (size_t)((H)*128     )*D_IN, &L[(P)*16384 + (H)*8192 + tid*8]); \
  gload_lds16(aStg + (T)*64 + (size_t)((H)*128 + 64)*D_IN, &L[(P)*16384 + (H)*8192 + 4096 + tid*8]); \
}while(0)
#define SGHB(T, P, H) do{ \
  gload_lds16(bStg + (T)*64 + (size_t)((H)*128     )*D_IN, &L[32768 + (P)*16384 + (H)*8192 + tid*8]); \
  gload_lds16(bStg + (T)*64 + (size_t)((H)*128 + 64)*D_IN, &L[32768 + (P)*16384 + (H)*8192 + 4096 + tid*8]); \
}while(0)

#define LDAQ(P, MQ) do{ \
  _Pragma("unroll") for (int mf=0;mf<4;++mf){ \
    const int rb_ = ((P)*16384) + (wm*128 + (MQ)*64 + mf*16 + fr)*64; \
    aq[mf][0] = *(const s16x8*)&L[rb_ + o0]; \
    aq[mf][1] = *(const s16x8*)&L[rb_ + o1]; } \
}while(0)
#define LDBQ(P, NQ, BQ) do{ \
  _Pragma("unroll") for (int nf=0;nf<2;++nf){ \
    const int rb_ = (32768 + (P)*16384) + (wn*64 + (NQ)*32 + nf*16 + fr)*64; \
    BQ[nf][0] = *(const s16x8*)&L[rb_ + o0]; \
    BQ[nf][1] = *(const s16x8*)&L[rb_ + o1]; } \
}while(0)

#define MFQ(MQ, NQ, BQ) do{ \
  __builtin_amdgcn_s_setprio(1); \
  _Pragma("unroll") for (int mf=0;mf<4;++mf) \
    _Pragma("unroll") for (int nf=0;nf<2;++nf){ \
      acc[(MQ)*4+mf][(NQ)*2+nf] = __builtin_amdgcn_mfma_f32_16x16x32_bf16(aq[mf][0], BQ[nf][0], acc[(MQ)*4+mf][(NQ)*2+nf],0,0,0); \
      acc[(MQ)*4+mf][(NQ)*2+nf] = __builtin_amdgcn_mfma_f32_16x16x32_bf16(aq[mf][1], BQ[nf][1], acc[(MQ)*4+mf][(NQ)*2+nf],0,0,0); } \
  __builtin_amdgcn_s_setprio(0); \
}while(0)

// one barrier + one vmcnt per K-tile; reads/MFMAs free-ordered (compiler lgkmcnt).
// Safety: all reads of buf P complete before each wave's BAR (every read feeds an MFMA
// pre-BAR); stage into P happens post-BAR next tile -> no WAR. Stage(t+1,Q) drained by
// VMW(0) (issued ~full tile earlier -> latency covered).
#define KT1B(P, Q, T1, ST) do{ \
  if (ST){ SGHA(T1, Q, 0); SGHA(T1, Q, 1); SGHB(T1, Q, 0); SGHB(T1, Q, 1); } \
  LDAQ(P, 0); LDBQ(P, 0, bq0); \
  MFQ(0,0,bq0); \
  LDBQ(P, 1, bq1); \
  MFQ(0,1,bq1); \
  LDAQ(P, 1); \
  MFQ(1,0,bq0); \
  MFQ(1,1,bq1); \
  VMW(0); BAR; \
}while(0)

__global__ __launch_bounds__(512, 2) void gemm1_kernel(
    const u16* __restrict__ Xb, const u16* __restrict__ W1T,
    const float* __restrict__ b1c, u16* __restrict__ Hb)
{
  __shared__ __attribute__((aligned(16))) u16 L[65536];
  const int tid  = threadIdx.x;
  const int lane = tid & 63;
  const int wid  = tid >> 6;
  const int wm   = wid >> 2;          // 0..1
  const int wn   = wid & 3;           // 0..3

  const int bid = blockIdx.x;
  const int xcd = bid & 7, pos = bid >> 3;
  const int mt  = xcd*8 + (pos & 7);
  const int nt  = pos >> 3;
  const int row0 = mt*256, col0 = nt*256;

  const int fr = lane & 15;
  const int kq = lane >> 4;
  const int l7 = fr & 7;
  const int o0 = ((kq     ^ l7) << 3);
  const int o1 = (((4+kq) ^ l7) << 3);

  const int sSl = (tid & 7) ^ ((tid >> 3) & 7);
  const u16* aStg = Xb  + (size_t)(row0 + (tid>>3))*D_IN + sSl*8;
  const u16* bStg = W1T + (size_t)(col0 + (tid>>3))*D_IN + sSl*8;

  f32x4 acc[8][4];
  const f32x4 fz = {0.f,0.f,0.f,0.f};
  #pragma unroll
  for (int m=0;m<8;++m)
    #pragma unroll
    for (int n=0;n<4;++n) acc[m][n] = fz;

  s16x8 aq[4][2], bq0[2][2], bq1[2][2];

  SGHA(0, 0, 0); SGHA(0, 0, 1);
  SGHB(0, 0, 0); SGHB(0, 0, 1);
  VMW(0); BAR;

  #pragma unroll 1
  for (int it=0; it<8; ++it){
    const int T = 2*it;
    KT1B(0, 1, T+1, 1);
    KT1B(1, 0, T+2, (it<7));
  }

  const int r4 = kq << 2;
  #pragma unroll
  for (int m=0;m<8;++m){
    const int gr = row0 + wm*128 + (m>>2)*64 + (m&3)*16 + r4;
    #pragma unroll
    for (int n=0;n<4;++n){
      const int gc = col0 + wn*64 + (n>>1)*32 + (n&1)*16 + fr;
      const float bias = b1c[gc];
      #pragma unroll
      for (int r=0;r<4;++r){
        float v = acc[m][n][r] + bias;
        v = v > 0.f ? v : 0.f;
        Hb[(size_t)(gr + r)*NW1P + gc] = f2bf(v);
      }
    }
  }
}

// ------- GEMM2 + fused gates: 256 blocks x 512 threads; shared experts computed ONCE -------
// Gates computed per 64-row band inline (reads Hb gate cols + gW2/gb2), softmax in-thread,
// stored to gsm LDS; then r12's deduped main loop (40 subtiles, compile-time expert in EPI).

#define SGA2(S, BUF) do{ \
  const u16* ga_ = Hb + (size_t)(row0 + (tid>>3))*NW1P + ((S)>>2)*256 + ((S)&3)*64 + sSl2*8; \
  gload_lds16(ga_, &LA[BUF][tid*8]); \
}while(0)

#define LOADB2(S, BV) do{ \
  const size_t base_ = ((size_t)(((S)>>2)*4 + wn)*16 + ((S)&3)*4)*512; \
  _Pragma("unroll") for (int kk=0;kk<4;++kk) \
    BV[kk] = *(const s16x8*)(pB2 + base_ + kk*512); \
}while(0)

#define COMPUTE2(BUF, BV) do{ \
  _Pragma("unroll") for (int kk=0;kk<4;++kk){ \
    const int row_ = wh*32 + l31; \
    s16x8 av = *(const s16x8*)&LA[BUF][(row_<<6) + (((((kk<<1)|l5)) ^ (row_&7))<<3)]; \
    __builtin_amdgcn_s_setprio(1); \
    eacc = __builtin_amdgcn_mfma_f32_32x32x16_bf16(av, BV[kk], eacc, 0, 0, 0); \
    __builtin_amdgcn_s_setprio(0); \
  } \
}while(0)

#define EPI2(PE) do{ \
  const float bias_ = bsm[(PE)*128 + wn*32 + l31]; \
  _Pragma("unroll") for (int r=0;r<16;++r){ \
    const int rl_ = wh*32 + 4*l5 + (r&3) + 8*(r>>2); \
    float v = eacc[r] + bias_; \
    v = v > 0.f ? v : 0.f; \
    if ((PE) < 4){ \
      oacc[0][r] += gsm[0*384 + rl_*6 + (PE)] * v; \
      oacc[1][r] += gsm[1*384 + rl_*6 + (PE)] * v; \
      oacc[2][r] += gsm[2*384 + rl_*6 + (PE)] * v; \
    } else { \
      oacc[((PE)-4)>>1][r] += gsm[(((PE)-4)>>1)*384 + rl_*6 + 4 + (((PE)-4)&1)] * v; \
    } \
    eacc[r] = 0.f; \
  } \
}while(0)

__global__ __launch_bounds__(512, 2) void gemm2_kernel(
    const u16* __restrict__ Hb, const u16* __restrict__ W2F,
    const float* __restrict__ b2c, const float* __restrict__ gW2,
    const float* __restrict__ gb2, float* __restrict__ outp)
{
  __shared__ __attribute__((aligned(16))) u16 LA[2][4096];  // 2 x 8 KB
  __shared__ float gsm[1152];      // gates: [g][64 rows][6]
  __shared__ float bsm[1280];      // biases for 10 physical experts
  __shared__ float wsm2[1170];     // gW2 (3*384) + gb2 (18)
  const int tid  = threadIdx.x;
  const int lane = tid & 63;
  const int wid  = tid >> 6;
  const int wh   = wid >> 2;          // 0..1 row half
  const int wn   = wid & 3;           // 0..3 col strip
  const int l31  = lane & 31, l5 = lane >> 5;

  const int bid  = blockIdx.x;        // 256 blocks: one 64-row band each
  const int row0 = bid*64;

  const int sSl2 = (tid & 7) ^ ((tid >> 3) & 7);
  const u16* pB2 = W2F + lane*8;

  // stage 0 + B frags early (in flight during gates compute)
  s16x8 bvA[4], bvB[4];
  SGA2(0, 0);
  LOADB2(0, bvA);

  for (int i = tid; i < 1152; i += 512) wsm2[i] = gW2[i];
  if (tid < 18) wsm2[1152 + tid] = gb2[tid];
  for (int i = tid; i < 1280; i += 512) bsm[i] = b2c[i];
  __syncthreads();   // wsm2 visible (also drains stage-0; acceptable once)

  // inline gates: threads 0..191 each own (row, g)
  if (tid < 192){
    const int row = tid & 63, g = tid >> 6;
    const u16* gh = Hb + (size_t)(row0 + row)*NW1P + 2560 + g*64;
    float lg[6];
    #pragma unroll
    for (int e=0;e<6;++e) lg[e] = wsm2[1152 + g*6 + e];
    #pragma unroll
    for (int k8=0;k8<8;++k8){
      u16x8 hv = *(const u16x8*)&gh[k8*8];
      #pragma unroll
      for (int j=0;j<8;++j){
        const float h = bf2f(hv[j]);
        const int k = k8*8 + j;
        #pragma unroll
        for (int e=0;e<6;++e) lg[e] += h * wsm2[g*384 + k*6 + e];
      }
    }
    float mx = lg[0];
    #pragma unroll
    for (int e=1;e<6;++e) mx = fmaxf(mx, lg[e]);
    float s = 0.f; float p[6];
    #pragma unroll
    for (int e=0;e<6;++e){ p[e] = expf(lg[e]-mx); s += p[e]; }
    const float inv = 1.f / s;
    #pragma unroll
    for (int e=0;e<6;++e) gsm[g*384 + row*6 + e] = p[e]*inv;
  }

  f32x16 eacc, oacc[3];
  #pragma unroll
  for (int r=0;r<16;++r){
    eacc[r] = 0.f; oacc[0][r] = 0.f; oacc[1][r] = 0.f; oacc[2][r] = 0.f;
  }
  __syncthreads();   // gsm visible

  #pragma unroll
  for (int i=0; i<20; ++i){   // fully unrolled: S and PE compile-time
    const int s = 2*i;
    SGA2(s+1, 1);
    LOADB2(s+1, bvB);
    COMPUTE2(0, bvA);
    VMW(4); BAR;
    if (i < 19){ SGA2(s+2, 0); LOADB2(s+2, bvA); }
    COMPUTE2(1, bvB);
    if (((s+1) & 3) == 3) EPI2((s+1) >> 2);
    VMW(4); BAR;
  }

  #pragma unroll
  for (int g=0; g<3; ++g){
    #pragma unroll
    for (int r=0;r<16;++r){
      const int rl = wh*32 + 4*l5 + (r&3) + 8*(r>>2);
      outp[((size_t)g*B_ROWS + row0 + rl)*H2N + wn*32 + l31] = oacc[g][r];
    }
  }
}

extern "C" void kernel_launch(void* const* d_in, const int* in_sizes, int n_in,
                              void* d_out, int out_size, void* d_ws, size_t ws_size,
                              hipStream_t stream)
{
  (void)in_sizes; (void)n_in; (void)out_size; (void)ws_size;
  const float* x   = (const float*)d_in[0];
  const float* sW1 = (const float*)d_in[2];
  const float* sb1 = (const float*)d_in[3];
  const float* sW2 = (const float*)d_in[4];
  const float* sb2 = (const float*)d_in[5];
  const float* dW1 = (const float*)d_in[6];
  const float* db1 = (const float*)d_in[7];
  const float* dW2 = (const float*)d_in[8];
  const float* db2 = (const float*)d_in[9];
  const float* gW1 = (const float*)d_in[10];
  const float* gb1 = (const float*)d_in[11];
  const float* gW2 = (const float*)d_in[12];
  const float* gb2 = (const float*)d_in[13];
  float* outp = (float*)d_out;

  char* ws = (char*)d_ws;
  u16*   Xb  = (u16*  )(ws + 0);          // 16384*1024*2 = 33554432
  u16*   W1T = (u16*  )(ws + 33554432);   // 2816*1024*2  =  5767168
  float* b1c = (float*)(ws + 39321600);   // 2816*4       =    11264
  u16*   W2F = (u16*  )(ws + 39332864);   // 10*4096*8*2  =   655360
  float* b2c = (float*)(ws + 39988224);   // 10*128*4     =     5120
  u16*   Hb  = (u16*  )(ws + 41172992);   // 16384*2816*2 = 92274688

  prep_kernel <<<dim3(9056), dim3(256), 0, stream>>>(sW1,dW1,gW1,sb1,db1,gb1,W1T,b1c,
                                                     sW2,dW2,sb2,db2,W2F,b2c, x, Xb);
  gemm1_kernel<<<dim3(704),  dim3(512), 0, stream>>>(Xb, W1T, b1c, Hb);
  gemm2_kernel<<<dim3(256),  dim3(512), 0, stream>>>(Hb, W2F, b2c, gW2, gb2, outp);
}

// Round 14
// 145.926 us; speedup vs baseline: 1.7042x; 1.0161x over previous
//
#include <hip/hip_runtime.h>

#define B_ROWS 16384
#define D_IN   1024
#define NW1P   2816   // padded GEMM1 N: 10*256 expert + 3*64 gate + 64 pad
#define H2N    128

typedef unsigned short u16;
typedef __attribute__((ext_vector_type(4)))  float f32x4;
typedef __attribute__((ext_vector_type(16))) float f32x16;
typedef __attribute__((ext_vector_type(8)))  short s16x8;
typedef __attribute__((ext_vector_type(8)))  unsigned short u16x8;

__device__ __forceinline__ u16 f2bf(float f){
  unsigned int u = __float_as_uint(f);
  u += 0x7FFFu + ((u >> 16) & 1u);
  return (u16)(u >> 16);
}
__device__ __forceinline__ float bf2f(u16 h){
  return __uint_as_float(((unsigned int)h) << 16);
}

// async global->LDS, 16B per lane. LDS dest must be linear (wave base + lane*16).
__device__ __forceinline__ void gload_lds16(const void* gp, void* lp){
  typedef __attribute__((address_space(1))) unsigned int GUI;
  typedef __attribute__((address_space(3))) unsigned int LUI;
  __builtin_amdgcn_global_load_lds((GUI*)(unsigned long long)gp,
                                   (LUI*)(unsigned int)(unsigned long long)lp,
                                   16, 0, 0);
}

// ---------------- merged prep: pack_w1 | pack_w2 | cast_x in one dispatch ----------------
__global__ void prep_kernel(const float* __restrict__ sW1, const float* __restrict__ dW1,
                            const float* __restrict__ gW1, const float* __restrict__ sb1,
                            const float* __restrict__ db1, const float* __restrict__ gb1,
                            u16* __restrict__ W1T, float* __restrict__ b1c,
                            const float* __restrict__ sW2, const float* __restrict__ dW2,
                            const float* __restrict__ sb2, const float* __restrict__ db2,
                            u16* __restrict__ W2F, float* __restrict__ b2c,
                            const float* __restrict__ x, u16* __restrict__ Xb)
{
  __shared__ float t[64*65];
  const int tid = threadIdx.x;
  const int bidg = blockIdx.x;

  if (bidg < 704){
    // ---- pack_w1: W1T[n][d] row-major bf16 ----
    const int bid = bidg;
    const int ntile = bid >> 4, dtile = bid & 15;
    const int n0 = ntile*64, d0 = dtile*64;
    #pragma unroll
    for (int i=0;i<16;++i){
      int idx = i*256 + tid;
      int dd = idx >> 6, nn = idx & 63;
      int n = n0 + nn, d = d0 + dd;
      float v;
      if (n < 2560){
        int e = n >> 8, h = n & 255;
        v = (e < 4) ? sW1[((size_t)e*D_IN + d)*256 + h]
                    : dW1[((size_t)(e-4)*D_IN + d)*256 + h];
      } else if (n < 2752){
        int t2 = n - 2560; int gg = t2 >> 6, k = t2 & 63;
        v = gW1[((size_t)gg*D_IN + d)*64 + k];
      } else v = 0.f;
      t[nn*65 + dd] = v;
    }
    __syncthreads();
    #pragma unroll
    for (int i=0;i<16;++i){
      int idx = i*256 + tid;
      int nn = idx >> 6, dd = idx & 63;
      W1T[(size_t)(n0+nn)*D_IN + d0 + dd] = f2bf(t[nn*65 + dd]);
    }
    if (dtile == 0 && tid < 64){
      int n = n0 + tid; float v;
      if (n < 2560){ int e = n>>8, h = n&255; v = (e<4)? sb1[e*256+h] : db1[(e-4)*256+h]; }
      else if (n < 2752){ int t2 = n-2560; v = gb1[(t2>>6)*64 + (t2&63)]; }
      else v = 0.f;
      b1c[n] = v;
    }
  } else if (bidg < 864){
    // ---- pack_w2: W2F fragment-packed ----
    const int bid = bidg - 704;          // 0..159
    const int e   = bid >> 4;
    const int sub = (bid & 15)*256 + tid;
    const int n32 = sub >> 10, k16 = (sub >> 6) & 15, lane = sub & 63;
    const int c   = n32*32 + (lane & 31);
    const int kb  = k16*16 + (lane >> 5)*8;
    u16 out[8];
    #pragma unroll
    for (int j=0;j<8;++j){
      const int k = kb + j;
      float v = (e < 4) ? sW2[((size_t)e*256 + k)*128 + c]
                        : dW2[((size_t)(e-4)*256 + k)*128 + c];
      out[j] = f2bf(v);
    }
    *(u16x8*)&W2F[(size_t)e*32768 + (size_t)sub*8] = *(u16x8*)out;
    if ((bid & 15) == 0 && tid < 128)
      b2c[e*128 + tid] = (e < 4) ? sb2[e*128 + tid] : db2[(e-4)*128 + tid];
  } else {
    // ---- cast_x ----
    const size_t i = ((size_t)(bidg - 864)*256 + tid)*8;
    f32x4 a = *(const f32x4*)(x + i);
    f32x4 b = *(const f32x4*)(x + i + 4);
    u16x8 r;
    r[0]=f2bf(a[0]); r[1]=f2bf(a[1]); r[2]=f2bf(a[2]); r[3]=f2bf(a[3]);
    r[4]=f2bf(b[0]); r[5]=f2bf(b[1]); r[6]=f2bf(b[2]); r[7]=f2bf(b[3]);
    *(u16x8*)(Xb + i) = r;
  }
}

// ---------------- GEMM1: r13 core (best measured: 112 us, 6-schedule ceiling) ----------------
#define BAR  __builtin_amdgcn_s_barrier()
#define VMW(N) asm volatile("s_waitcnt vmcnt(" #N ")" ::: "memory")

#define SGHA(T, P, H) do{ \
  gload_lds16(aStg + (T)*64 + (size_t)((H)*128     )*D_IN, &L[(P)*16384 + (H)*8192 + tid*8]); \
  gload_lds16(aStg + (T)*64 + (size_t)((H)*128 + 64)*D_IN, &L[(P)*16384 + (H)*8192 + 4096 + tid*8]); \
}while(0)
#define SGHB(T, P, H) do{ \
  gload_lds16(bStg + (T)*64 + (size_t)((H)*128     )*D_IN, &L[32768 + (P)*16384 + (H)*8192 + tid*8]); \
  gload_lds16(bStg + (T)*64 + (size_t)((H)*128 + 64)*D_IN, &L[32768 + (P)*16384 + (H)*8192 + 4096 + tid*8]); \
}while(0)

#define LDAQ(P, MQ) do{ \
  _Pragma("unroll") for (int mf=0;mf<4;++mf){ \
    const int rb_ = ((P)*16384) + (wm*128 + (MQ)*64 + mf*16 + fr)*64; \
    aq[mf][0] = *(const s16x8*)&L[rb_ + o0]; \
    aq[mf][1] = *(const s16x8*)&L[rb_ + o1]; } \
}while(0)
#define LDBQ(P, NQ, BQ) do{ \
  _Pragma("unroll") for (int nf=0;nf<2;++nf){ \
    const int rb_ = (32768 + (P)*16384) + (wn*64 + (NQ)*32 + nf*16 + fr)*64; \
    BQ[nf][0] = *(const s16x8*)&L[rb_ + o0]; \
    BQ[nf][1] = *(const s16x8*)&L[rb_ + o1]; } \
}while(0)

#define MFQ(MQ, NQ, BQ) do{ \
  __builtin_amdgcn_s_setprio(1); \
  _Pragma("unroll") for (int mf=0;mf<4;++mf) \
    _Pragma("unroll") for (int nf=0;nf<2;++nf){ \
      acc[(MQ)*4+mf][(NQ)*2+nf] = __builtin_amdgcn_mfma_f32_16x16x32_bf16(aq[mf][0], BQ[nf][0], acc[(MQ)*4+mf][(NQ)*2+nf],0,0,0); \
      acc[(MQ)*4+mf][(NQ)*2+nf] = __builtin_amdgcn_mfma_f32_16x16x32_bf16(aq[mf][1], BQ[nf][1], acc[(MQ)*4+mf][(NQ)*2+nf],0,0,0); } \
  __builtin_amdgcn_s_setprio(0); \
}while(0)

#define KT1B(P, Q, T1, ST) do{ \
  if (ST){ SGHA(T1, Q, 0); SGHA(T1, Q, 1); SGHB(T1, Q, 0); SGHB(T1, Q, 1); } \
  LDAQ(P, 0); LDBQ(P, 0, bq0); \
  MFQ(0,0,bq0); \
  LDBQ(P, 1, bq1); \
  MFQ(0,1,bq1); \
  LDAQ(P, 1); \
  MFQ(1,0,bq0); \
  MFQ(1,1,bq1); \
  VMW(0); BAR; \
}while(0)

__global__ __launch_bounds__(512, 2) void gemm1_kernel(
    const u16* __restrict__ Xb, const u16* __restrict__ W1T,
    const float* __restrict__ b1c, u16* __restrict__ Hb)
{
  __shared__ __attribute__((aligned(16))) u16 L[65536];
  const int tid  = threadIdx.x;
  const int lane = tid & 63;
  const int wid  = tid >> 6;
  const int wm   = wid >> 2;          // 0..1
  const int wn   = wid & 3;           // 0..3

  const int bid = blockIdx.x;
  const int xcd = bid & 7, pos = bid >> 3;
  const int mt  = xcd*8 + (pos & 7);
  const int nt  = pos >> 3;
  const int row0 = mt*256, col0 = nt*256;

  const int fr = lane & 15;
  const int kq = lane >> 4;
  const int l7 = fr & 7;
  const int o0 = ((kq     ^ l7) << 3);
  const int o1 = (((4+kq) ^ l7) << 3);

  const int sSl = (tid & 7) ^ ((tid >> 3) & 7);
  const u16* aStg = Xb  + (size_t)(row0 + (tid>>3))*D_IN + sSl*8;
  const u16* bStg = W1T + (size_t)(col0 + (tid>>3))*D_IN + sSl*8;

  f32x4 acc[8][4];
  const f32x4 fz = {0.f,0.f,0.f,0.f};
  #pragma unroll
  for (int m=0;m<8;++m)
    #pragma unroll
    for (int n=0;n<4;++n) acc[m][n] = fz;

  s16x8 aq[4][2], bq0[2][2], bq1[2][2];

  SGHA(0, 0, 0); SGHA(0, 0, 1);
  SGHB(0, 0, 0); SGHB(0, 0, 1);
  VMW(0); BAR;

  #pragma unroll 1
  for (int it=0; it<8; ++it){
    const int T = 2*it;
    KT1B(0, 1, T+1, 1);
    KT1B(1, 0, T+2, (it<7));
  }

  const int r4 = kq << 2;
  #pragma unroll
  for (int m=0;m<8;++m){
    const int gr = row0 + wm*128 + (m>>2)*64 + (m&3)*16 + r4;
    #pragma unroll
    for (int n=0;n<4;++n){
      const int gc = col0 + wn*64 + (n>>1)*32 + (n&1)*16 + fr;
      const float bias = b1c[gc];
      #pragma unroll
      for (int r=0;r<4;++r){
        float v = acc[m][n][r] + bias;
        v = v > 0.f ? v : 0.f;
        Hb[(size_t)(gr + r)*NW1P + gc] = f2bf(v);
      }
    }
  }
}

// ------- GEMM2 + fused gates v4: 512 blocks x 256 threads, 32-row bands, 2 blocks/CU -------
// 4 waves = 4 col strips (wn); wave tile 32x32 per expert; eacc(16)+oacc[3](48)=64 acc VGPR.
// Zero grid tail (512 = 2 x 256 CUs). Shared experts computed once (dedup).
// 40 K-subtiles fully unrolled (compile-time expert in EPI2 -- rule #20).

#define SGA2(S, BUF) do{ \
  const u16* ga_ = Hb + (size_t)(row0 + (tid>>3))*NW1P + ((S)>>2)*256 + ((S)&3)*64 + sSl2*8; \
  gload_lds16(ga_, &LA[BUF][tid*8]); \
}while(0)

#define LOADB2(S, BV) do{ \
  const size_t base_ = ((size_t)(((S)>>2)*4 + wn)*16 + ((S)&3)*4)*512; \
  _Pragma("unroll") for (int kk=0;kk<4;++kk) \
    BV[kk] = *(const s16x8*)(pB2 + base_ + kk*512); \
}while(0)

#define COMPUTE2(BUF, BV) do{ \
  _Pragma("unroll") for (int kk=0;kk<4;++kk){ \
    const int row_ = l31; \
    s16x8 av = *(const s16x8*)&LA[BUF][(row_<<6) + (((((kk<<1)|l5)) ^ (row_&7))<<3)]; \
    __builtin_amdgcn_s_setprio(1); \
    eacc = __builtin_amdgcn_mfma_f32_32x32x16_bf16(av, BV[kk], eacc, 0, 0, 0); \
    __builtin_amdgcn_s_setprio(0); \
  } \
}while(0)

#define EPI2(PE) do{ \
  const float bias_ = bsm[(PE)*128 + wn*32 + l31]; \
  _Pragma("unroll") for (int r=0;r<16;++r){ \
    const int rl_ = 4*l5 + (r&3) + 8*(r>>2); \
    float v = eacc[r] + bias_; \
    v = v > 0.f ? v : 0.f; \
    if ((PE) < 4){ \
      oacc[0][r] += gsm[0*192 + rl_*6 + (PE)] * v; \
      oacc[1][r] += gsm[1*192 + rl_*6 + (PE)] * v; \
      oacc[2][r] += gsm[2*192 + rl_*6 + (PE)] * v; \
    } else { \
      oacc[((PE)-4)>>1][r] += gsm[(((PE)-4)>>1)*192 + rl_*6 + 4 + (((PE)-4)&1)] * v; \
    } \
    eacc[r] = 0.f; \
  } \
}while(0)

__global__ __launch_bounds__(256, 2) void gemm2_kernel(
    const u16* __restrict__ Hb, const u16* __restrict__ W2F,
    const float* __restrict__ b2c, const float* __restrict__ gW2,
    const float* __restrict__ gb2, float* __restrict__ outp)
{
  __shared__ __attribute__((aligned(16))) u16 LA[2][2048];  // 2 x 4 KB (32 rows x 64 k)
  __shared__ float gsm[576];       // gates: [g][32 rows][6]
  __shared__ float bsm[1280];      // biases for 10 physical experts
  __shared__ float wsm2[1170];     // gW2 (3*384) + gb2 (18)
  const int tid  = threadIdx.x;
  const int lane = tid & 63;
  const int wn   = tid >> 6;          // 0..3 col strip
  const int l31  = lane & 31, l5 = lane >> 5;

  const int bid  = blockIdx.x;        // 512 blocks: one 32-row band each (2/CU, no tail)
  const int row0 = bid*32;

  const int sSl2 = (tid & 7) ^ ((tid >> 3) & 7);
  const u16* pB2 = W2F + lane*8;

  // stage 0 + B frags early (in flight during gates compute)
  s16x8 bvA[4], bvB[4];
  SGA2(0, 0);
  LOADB2(0, bvA);

  for (int i = tid; i < 1152; i += 256) wsm2[i] = gW2[i];
  if (tid < 18) wsm2[1152 + tid] = gb2[tid];
  for (int i = tid; i < 1280; i += 256) bsm[i] = b2c[i];
  __syncthreads();   // wsm2/bsm visible (drains stage-0 too; once, acceptable)

  // inline gates: threads 0..95 each own (row, g)
  if (tid < 96){
    const int row = tid & 31, g = tid >> 5;
    const u16* gh = Hb + (size_t)(row0 + row)*NW1P + 2560 + g*64;
    float lg[6];
    #pragma unroll
    for (int e=0;e<6;++e) lg[e] = wsm2[1152 + g*6 + e];
    #pragma unroll
    for (int k8=0;k8<8;++k8){
      u16x8 hv = *(const u16x8*)&gh[k8*8];
      #pragma unroll
      for (int j=0;j<8;++j){
        const float h = bf2f(hv[j]);
        const int k = k8*8 + j;
        #pragma unroll
        for (int e=0;e<6;++e) lg[e] += h * wsm2[g*384 + k*6 + e];
      }
    }
    float mx = lg[0];
    #pragma unroll
    for (int e=1;e<6;++e) mx = fmaxf(mx, lg[e]);
    float s = 0.f; float p[6];
    #pragma unroll
    for (int e=0;e<6;++e){ p[e] = expf(lg[e]-mx); s += p[e]; }
    const float inv = 1.f / s;
    #pragma unroll
    for (int e=0;e<6;++e) gsm[g*192 + row*6 + e] = p[e]*inv;
  }

  f32x16 eacc, oacc[3];
  #pragma unroll
  for (int r=0;r<16;++r){
    eacc[r] = 0.f; oacc[0][r] = 0.f; oacc[1][r] = 0.f; oacc[2][r] = 0.f;
  }
  __syncthreads();   // gsm visible

  #pragma unroll
  for (int i=0; i<20; ++i){   // fully unrolled: S and PE compile-time
    const int s = 2*i;
    SGA2(s+1, 1);
    LOADB2(s+1, bvB);
    COMPUTE2(0, bvA);
    VMW(4); BAR;              // waits the 1 gld_lds; 4 b128 ride across
    if (i < 19){ SGA2(s+2, 0); LOADB2(s+2, bvA); }
    COMPUTE2(1, bvB);
    if (((s+1) & 3) == 3) EPI2((s+1) >> 2);
    VMW(4); BAR;
  }

  #pragma unroll
  for (int g=0; g<3; ++g){
    #pragma unroll
    for (int r=0;r<16;++r){
      const int rl = 4*l5 + (r&3) + 8*(r>>2);
      outp[((size_t)g*B_ROWS + row0 + rl)*H2N + wn*32 + l31] = oacc[g][r];
    }
  }
}

extern "C" void kernel_launch(void* const* d_in, const int* in_sizes, int n_in,
                              void* d_out, int out_size, void* d_ws, size_t ws_size,
                              hipStream_t stream)
{
  (void)in_sizes; (void)n_in; (void)out_size; (void)ws_size;
  const float* x   = (const float*)d_in[0];
  const float* sW1 = (const float*)d_in[2];
  const float* sb1 = (const float*)d_in[3];
  const float* sW2 = (const float*)d_in[4];
  const float* sb2 = (const float*)d_in[5];
  const float* dW1 = (const float*)d_in[6];
  const float* db1 = (const float*)d_in[7];
  const float* dW2 = (const float*)d_in[8];
  const float* db2 = (const float*)d_in[9];
  const float* gW1 = (const float*)d_in[10];
  const float* gb1 = (const float*)d_in[11];
  const float* gW2 = (const float*)d_in[12];
  const float* gb2 = (const float*)d_in[13];
  float* outp = (float*)d_out;

  char* ws = (char*)d_ws;
  u16*   Xb  = (u16*  )(ws + 0);          // 16384*1024*2 = 33554432
  u16*   W1T = (u16*  )(ws + 33554432);   // 2816*1024*2  =  5767168
  float* b1c = (float*)(ws + 39321600);   // 2816*4       =    11264
  u16*   W2F = (u16*  )(ws + 39332864);   // 10*4096*8*2  =   655360
  float* b2c = (float*)(ws + 39988224);   // 10*128*4     =     5120
  u16*   Hb  = (u16*  )(ws + 41172992);   // 16384*2816*2 = 92274688

  prep_kernel <<<dim3(9056), dim3(256), 0, stream>>>(sW1,dW1,gW1,sb1,db1,gb1,W1T,b1c,
                                                     sW2,dW2,sb2,db2,W2F,b2c, x, Xb);
  gemm1_kernel<<<dim3(704),  dim3(512), 0, stream>>>(Xb, W1T, b1c, Hb);
  gemm2_kernel<<<dim3(512),  dim3(256), 0, stream>>>(Hb, W2F, b2c, gW2, gb2, outp);
}